// Round 6
// baseline (144.948 us; speedup 1.0000x reference)
//
#include <hip/hip_runtime.h>
#include <cstdint>
#include <cstddef>

// Problem constants: B=2, T=2048, C=1024, H=16, D=64
#define SEQ_T 2048
#define NHEAD 16

typedef __attribute__((ext_vector_type(8))) short short8;
typedef __attribute__((ext_vector_type(4))) float f32x4;
typedef __attribute__((ext_vector_type(16))) float f32x16;

__device__ __forceinline__ unsigned short f2bf(float f) {
  union { float f; unsigned int u; } v; v.f = f;
  return (unsigned short)((v.u + 0x7FFFu + ((v.u >> 16) & 1u)) >> 16);
}

__device__ __forceinline__ unsigned cvtpk(float lo, float hi) {
  unsigned r;
  asm("v_cvt_pk_bf16_f32 %0, %1, %2" : "=v"(r) : "v"(lo), "v"(hi));
  return r;
}

// permlane32_swap: vdst hi-32-lanes <-> vsrc lo-32-lanes.
// MUST go through the builtin (or be s_nop-padded): permlane has VALU RAW
// hazard wait-states the compiler only inserts for the intrinsic form.
#if __has_builtin(__builtin_amdgcn_permlane32_swap)
__device__ __forceinline__ void plswap(unsigned& a, unsigned& b) {
  auto r = __builtin_amdgcn_permlane32_swap(a, b, false, false);
  a = r[0];
  b = r[1];
}
#else
__device__ __forceinline__ void plswap(unsigned& a, unsigned& b) {
  asm volatile("s_nop 1\n\tv_permlane32_swap_b32 %0, %1\n\ts_nop 1"
               : "+v"(a), "+v"(b));
}
#endif

// cross-half (lane^32) reductions built on plswap
__device__ __forceinline__ float xhalf_max(float x) {
  unsigned a = __builtin_bit_cast(unsigned, x), b = a;
  plswap(a, b);
  return fmaxf(__builtin_bit_cast(float, a), __builtin_bit_cast(float, b));
}
__device__ __forceinline__ float xhalf_add(float x) {
  unsigned a = __builtin_bit_cast(unsigned, x), b = a;
  plswap(a, b);
  return __builtin_bit_cast(float, a) + __builtin_bit_cast(float, b);
}

__device__ __forceinline__ float vmax16(const f32x16 v) {
  float a0 = fmaxf(v[0], v[8]),  a1 = fmaxf(v[1], v[9]);
  float a2 = fmaxf(v[2], v[10]), a3 = fmaxf(v[3], v[11]);
  float a4 = fmaxf(v[4], v[12]), a5 = fmaxf(v[5], v[13]);
  float a6 = fmaxf(v[6], v[14]), a7 = fmaxf(v[7], v[15]);
  float b0 = fmaxf(a0, a4), b1 = fmaxf(a1, a5);
  float b2 = fmaxf(a2, a6), b3 = fmaxf(a3, a7);
  return fmaxf(fmaxf(b0, b1), fmaxf(b2, b3));
}

__device__ __forceinline__ void gl_lds16(const void* g, void* l) {
  __builtin_amdgcn_global_load_lds(
      (__attribute__((address_space(1))) void*)(void*)g,
      (__attribute__((address_space(3))) void*)l, 16, 0, 0);
}

// ---------- fp32 -> bf16 convert (vectorized) ----------
__global__ void k_cvt(const float* __restrict__ in, unsigned short* __restrict__ out, int n4) {
  int i = blockIdx.x * 256 + threadIdx.x;
  if (i >= n4) return;
  float4 v = ((const float4*)in)[i];
  unsigned long long pk = (unsigned long long)f2bf(v.x)
                        | ((unsigned long long)f2bf(v.y) << 16)
                        | ((unsigned long long)f2bf(v.z) << 32)
                        | ((unsigned long long)f2bf(v.w) << 48);
  ((unsigned long long*)out)[i] = pk;
}

// ---------- [K,N] fp32 -> [N,K] bf16 transpose-convert ----------
__global__ void k_tr(const float* __restrict__ in, unsigned short* __restrict__ out, int K, int N) {
  int idx = blockIdx.x * 256 + threadIdx.x;
  int n = idx % N;
  int k0 = (idx / N) * 8;
  short8 v;
#pragma unroll
  for (int j = 0; j < 8; ++j)
    v[j] = (short)f2bf(in[(size_t)(k0 + j) * N + n]);
  *(short8*)&out[(size_t)n * K + k0] = v;
}

// ---------- RoPE cos/sin table [T][32] ----------
__global__ void k_tab(float2* __restrict__ tab) {
  int idx = blockIdx.x * 256 + threadIdx.x;
  int t = idx >> 5, i = idx & 31;
  float inv = powf(10000.0f, -(float)(2 * i) / 64.0f);
  float f = (float)t * inv;
  tab[idx] = make_float2(cosf(f), sinf(f));
}

// ---------- GEMM1: qkv = x @ W_attn^T(+b), fused RoPE; q/k -> [B,H,T,D], v -> V^T [B,H,D,T] ----------
__global__ void k_gemm_qkv(const unsigned short* __restrict__ A,
                           const unsigned short* __restrict__ Bt,
                           const float* __restrict__ bias,
                           const float2* __restrict__ cs,
                           unsigned short* __restrict__ qo,
                           unsigned short* __restrict__ ko,
                           unsigned short* __restrict__ vo) {
  __shared__ unsigned short lA[128 * 32];
  __shared__ unsigned short lB[128 * 32];
  const int K = 1024;
  const int bn = blockIdx.x, bm = blockIdx.y;
  const int tid = threadIdx.x, w = tid >> 6, l = tid & 63;
  const int lr = l & 15, lh = l >> 4;
  const int wm = w >> 1, wn = w & 1;

  f32x4 acc[4][4];
#pragma unroll
  for (int m = 0; m < 4; ++m)
#pragma unroll
    for (int n = 0; n < 4; ++n)
#pragma unroll
      for (int i = 0; i < 4; ++i) acc[m][n][i] = 0.f;

  const unsigned short* ga0 = A + (size_t)(bm * 128 + w * 16 + (l >> 2)) * K + (l & 3) * 8;
  const unsigned short* gb0 = Bt + (size_t)(bn * 128 + w * 16 + (l >> 2)) * K + (l & 3) * 8;
  unsigned short* la0 = &lA[w * 512];
  unsigned short* la1 = &lA[(w + 4) * 512];
  unsigned short* lb0 = &lB[w * 512];
  unsigned short* lb1 = &lB[(w + 4) * 512];

  for (int kt = 0; kt < K; kt += 32) {
    gl_lds16(ga0 + kt, la0);
    gl_lds16(ga0 + (size_t)64 * K + kt, la1);
    gl_lds16(gb0 + kt, lb0);
    gl_lds16(gb0 + (size_t)64 * K + kt, lb1);
    __syncthreads();
    short8 af[4], bf[4];
#pragma unroll
    for (int m = 0; m < 4; ++m) af[m] = *(const short8*)&lA[(wm * 64 + m * 16 + lr) * 32 + lh * 8];
#pragma unroll
    for (int n = 0; n < 4; ++n) bf[n] = *(const short8*)&lB[(wn * 64 + n * 16 + lr) * 32 + lh * 8];
#pragma unroll
    for (int m = 0; m < 4; ++m)
#pragma unroll
      for (int n = 0; n < 4; ++n)
        acc[m][n] = __builtin_amdgcn_mfma_f32_16x16x32_bf16(af[m], bf[n], acc[m][n], 0, 0, 0);
    __syncthreads();
  }

  const int col0 = bn * 128 + wn * 64;
  const int row0 = bm * 128 + wm * 64;
  const int sec = col0 >> 10;
  const int hh = (col0 >> 6) & 15;
  float bl[4];
#pragma unroll
  for (int n = 0; n < 4; ++n) bl[n] = bias[col0 + n * 16 + lr];

  if (sec == 2) {
    // V^T epilogue: vo is [B*H][D=64][T=2048]
    const int b = row0 >> 11;
    unsigned short* vtp = vo + (size_t)(b * 16 + hh) * 64 * 2048;
#pragma unroll
    for (int n = 0; n < 4; ++n) {
      int d = n * 16 + lr;
#pragma unroll
      for (int m = 0; m < 4; ++m) {
        int t = (row0 + m * 16 + lh * 4) & 2047;
        unsigned long long pk = (unsigned long long)f2bf(acc[m][n][0] + bl[n])
                              | ((unsigned long long)f2bf(acc[m][n][1] + bl[n]) << 16)
                              | ((unsigned long long)f2bf(acc[m][n][2] + bl[n]) << 32)
                              | ((unsigned long long)f2bf(acc[m][n][3] + bl[n]) << 48);
        *(unsigned long long*)&vtp[(size_t)d * 2048 + t] = pk;
      }
    }
  } else {
    unsigned short* dst = (sec == 0) ? qo : ko;
#pragma unroll
    for (int m = 0; m < 4; ++m)
#pragma unroll
      for (int i = 0; i < 4; ++i) {
        int row = row0 + m * 16 + lh * 4 + i;
        int t = row & 2047, b = row >> 11;
        size_t ob = ((size_t)(b * 16 + hh) * 2048 + t) * 64;
#pragma unroll
        for (int n = 0; n < 4; ++n) {
          float v = acc[m][n][i] + bl[n];
          float pv = acc[m][n ^ 2][i] + bl[n ^ 2];
          int d = n * 16 + lr;
          float2 c = cs[t * 32 + (d & 31)];
          float rot = (d < 32) ? -pv : pv;
          dst[ob + d] = f2bf(v * c.x + rot * c.y);
        }
      }
  }
}

// ---------- flash attention, 32x32 MFMA structure ----------
// grid 512 (XCD-chunked: 4 heads x 16 qt per XCD, qt balanced-permuted), 256 thr.
// QBLK=128 (32 q/wave), KVBLK=128, K/V double-buffered in LDS.
// Swapped QK^T (S^T = mfma(K,Q)): lane&31 = q, 16 regs = kv half-rows; partner lane^32
// holds complementary kv. Softmax + P->A-frag fully in-register (cvt_pk + permlane32_swap).
__global__ __launch_bounds__(256, 2) void k_attn(const unsigned short* __restrict__ Q,
                       const unsigned short* __restrict__ Kg,
                       const unsigned short* __restrict__ VT,
                       unsigned short* __restrict__ O) {
  __shared__ unsigned short kl[2][128 * 64];   // [kv][d], chunk-swizzled ^(kv&7)
  __shared__ unsigned short vl[2][64 * 128];   // [d][kv], chunk-swizzled ^(d&15)
  const int id = blockIdx.x;
  const int xcd = id & 7, u = id >> 3;
  const int bh = xcd * 4 + (u >> 4);
  const int s = u & 15;
  const int qt = (s & 1) ? (15 - (s >> 1)) : (s >> 1);
  const int tid = threadIdx.x, w = tid >> 6, l = tid & 63;
  const int lq = l & 31, hi = l >> 5;
  const size_t base = (size_t)bh * SEQ_T * 64;
  const float CE = 0.18033688f;   // 0.125 * log2(e)
  const float DTHR = 44.3614f;    // 8 / CE

  // Q fragments (B-operand): lane holds Q[qrow][c*16 + hi*8 + j]
  const int qrow = qt * 128 + w * 32 + lq;
  short8 qf[4];
#pragma unroll
  for (int c = 0; c < 4; ++c)
    qf[c] = *(const short8*)&Q[base + (size_t)qrow * 64 + c * 16 + hi * 8];

  // staging source bases (pre-swizzled global source, linear LDS dest)
  const int kv0 = tid >> 3;
  const unsigned short* ks0 = Kg + base + (size_t)kv0 * 64 + (((tid & 7) ^ (kv0 & 7)) * 8);
  const int dv0 = tid >> 4;
  const unsigned short* vs0 = VT + base + (size_t)dv0 * 2048 + (((tid & 15) ^ dv0) * 8);

#define STAGE(KT, BSEL) do { \
    const unsigned short* kp_ = ks0 + (size_t)(KT) * 8192; \
    const unsigned short* vp_ = vs0 + (size_t)(KT) * 128;  \
    unsigned short* kd_ = &kl[BSEL][w * 512]; \
    unsigned short* vd_ = &vl[BSEL][w * 512]; \
    gl_lds16(kp_,        kd_);        gl_lds16(kp_ + 2048,  kd_ + 2048); \
    gl_lds16(kp_ + 4096, kd_ + 4096); gl_lds16(kp_ + 6144,  kd_ + 6144); \
    gl_lds16(vp_,         vd_);        gl_lds16(vp_ + 32768, vd_ + 2048); \
    gl_lds16(vp_ + 65536, vd_ + 4096); gl_lds16(vp_ + 98304, vd_ + 6144); \
  } while (0)

  float mi = -3.0e38f, li = 0.f;
  f32x16 oc0, oc1;
#pragma unroll
  for (int r = 0; r < 16; ++r) { oc0[r] = 0.f; oc1[r] = 0.f; }

  const int nkt = qt + 1;
  STAGE(0, 0);
  __syncthreads();

  for (int kt = 0; kt < nkt; ++kt) {
    const int cur = kt & 1;
    if (kt + 1 < nkt) STAGE(kt + 1, cur ^ 1);
    const unsigned short* kb = &kl[cur][0];
    const unsigned short* vb = &vl[cur][0];

    // S^T = K Q^T : 4 kv-tiles of 32
    f32x16 st[4];
#pragma unroll
    for (int tt = 0; tt < 4; ++tt)
#pragma unroll
      for (int r = 0; r < 16; ++r) st[tt][r] = 0.f;

    __builtin_amdgcn_s_setprio(1);
#pragma unroll
    for (int tt = 0; tt < 4; ++tt) {
      const int rowb = (tt * 32 + lq) * 64;
#pragma unroll
      for (int c = 0; c < 4; ++c) {
        const short8 kf = *(const short8*)&kb[rowb + (((c * 2 + hi) ^ (l & 7)) * 8)];
        st[tt] = __builtin_amdgcn_mfma_f32_32x32x16_bf16(kf, qf[c], st[tt], 0, 0, 0);
      }
    }
    __builtin_amdgcn_s_setprio(0);

    if (kt == nkt - 1) {   // diagonal: causal mask (unscaled scores)
#pragma unroll
      for (int tt = 0; tt < 4; ++tt)
#pragma unroll
        for (int r = 0; r < 16; ++r) {
          int kvg = kt * 128 + tt * 32 + (r & 3) + 8 * (r >> 2) + 4 * hi;
          if (kvg > qrow) st[tt][r] = -3.0e38f;
        }
    }

    // tile max over own 64 + partner half
    float tm = fmaxf(fmaxf(vmax16(st[0]), vmax16(st[1])),
                     fmaxf(vmax16(st[2]), vmax16(st[3])));
    tm = xhalf_max(tm);

    // T13 defer-rescale
    if (!__all(tm <= mi + DTHR)) {
      float mn = fmaxf(mi, tm);
      float scq = exp2f((mi - mn) * CE);
      mi = mn;
      li *= scq;
#pragma unroll
      for (int r = 0; r < 16; ++r) {
        float sc_r = __shfl(scq, (r & 3) + 8 * (r >> 2) + 4 * hi, 64);
        oc0[r] *= sc_r;
        oc1[r] *= sc_r;
      }
    }

    // exp pass (in place) + row sum
    const float nb = mi * CE;
    float rs0 = 0.f, rs1 = 0.f;
#pragma unroll
    for (int tt = 0; tt < 4; ++tt)
#pragma unroll
      for (int r = 0; r < 16; ++r) {
        float p = exp2f(fmaf(st[tt][r], CE, -nb));
        st[tt][r] = p;
        if (r & 1) rs1 += p; else rs0 += p;
      }
    li += xhalf_add(rs0 + rs1);

    // pack P into PV A-fragments: per 16-kv block, 4 cvt_pk + 2 permlane32_swap
    short8 pa[8];
#pragma unroll
    for (int kc = 0; kc < 8; ++kc) {
      const int tt = kc >> 1, o = (kc & 1) * 8;
      unsigned w0 = cvtpk(st[tt][o + 0], st[tt][o + 1]);
      unsigned w1 = cvtpk(st[tt][o + 2], st[tt][o + 3]);
      unsigned w2 = cvtpk(st[tt][o + 4], st[tt][o + 5]);
      unsigned w3 = cvtpk(st[tt][o + 6], st[tt][o + 7]);
      plswap(w0, w2);
      plswap(w1, w3);
      uint4 F;
      F.x = w0; F.y = w1; F.z = w2; F.w = w3;
      pa[kc] = __builtin_bit_cast(short8, F);
    }

    // O += P V : 8 k-chunks x 2 d-tiles
    __builtin_amdgcn_s_setprio(1);
#pragma unroll
    for (int kc = 0; kc < 8; ++kc) {
      const int chs = ((kc * 2 + hi) ^ (lq & 15)) * 8;
      const short8 vb0 = *(const short8*)&vb[lq * 128 + chs];
      oc0 = __builtin_amdgcn_mfma_f32_32x32x16_bf16(pa[kc], vb0, oc0, 0, 0, 0);
      const short8 vb1 = *(const short8*)&vb[(32 + lq) * 128 + chs];
      oc1 = __builtin_amdgcn_mfma_f32_32x32x16_bf16(pa[kc], vb1, oc1, 0, 0, 0);
    }
    __builtin_amdgcn_s_setprio(0);

    if (kt + 1 < nkt) __syncthreads();
  }

  // epilogue: divide by row-sum (li synced across halves), write O [B,T,C] bf16
  const int hh = bh & 15, bb = bh >> 4;
#pragma unroll
  for (int r = 0; r < 16; ++r) {
    const int qloc = (r & 3) + 8 * (r >> 2) + 4 * hi;
    float lr_ = __shfl(li, qloc, 64);
    float inv = 1.0f / lr_;
    int qg = qt * 128 + w * 32 + qloc;
    size_t ob = (size_t)(bb * 2048 + qg) * 1024 + hh * 64;
    O[ob + lq]      = f2bf(oc0[r] * inv);
    O[ob + 32 + lq] = f2bf(oc1[r] * inv);
  }
#undef STAGE
}

// ---------- GEMM2: out = attn_out @ W_proj^T + b (fp32 out) ----------
__global__ void k_gemm_proj(const unsigned short* __restrict__ A,
                            const unsigned short* __restrict__ Bt,
                            const float* __restrict__ bias,
                            float* __restrict__ out) {
  __shared__ unsigned short lA[128 * 32];
  __shared__ unsigned short lB[128 * 32];
  const int K = 1024;
  const int bn = blockIdx.x, bm = blockIdx.y;
  const int tid = threadIdx.x, w = tid >> 6, l = tid & 63;
  const int lr = l & 15, lh = l >> 4;
  const int wm = w >> 1, wn = w & 1;

  f32x4 acc[4][4];
#pragma unroll
  for (int m = 0; m < 4; ++m)
#pragma unroll
    for (int n = 0; n < 4; ++n)
#pragma unroll
      for (int i = 0; i < 4; ++i) acc[m][n][i] = 0.f;

  const unsigned short* ga0 = A + (size_t)(bm * 128 + w * 16 + (l >> 2)) * K + (l & 3) * 8;
  const unsigned short* gb0 = Bt + (size_t)(bn * 128 + w * 16 + (l >> 2)) * K + (l & 3) * 8;
  unsigned short* la0 = &lA[w * 512];
  unsigned short* la1 = &lA[(w + 4) * 512];
  unsigned short* lb0 = &lB[w * 512];
  unsigned short* lb1 = &lB[(w + 4) * 512];

  for (int kt = 0; kt < K; kt += 32) {
    gl_lds16(ga0 + kt, la0);
    gl_lds16(ga0 + (size_t)64 * K + kt, la1);
    gl_lds16(gb0 + kt, lb0);
    gl_lds16(gb0 + (size_t)64 * K + kt, lb1);
    __syncthreads();
    short8 af[4], bf[4];
#pragma unroll
    for (int m = 0; m < 4; ++m) af[m] = *(const short8*)&lA[(wm * 64 + m * 16 + lr) * 32 + lh * 8];
#pragma unroll
    for (int n = 0; n < 4; ++n) bf[n] = *(const short8*)&lB[(wn * 64 + n * 16 + lr) * 32 + lh * 8];
#pragma unroll
    for (int m = 0; m < 4; ++m)
#pragma unroll
      for (int n = 0; n < 4; ++n)
        acc[m][n] = __builtin_amdgcn_mfma_f32_16x16x32_bf16(af[m], bf[n], acc[m][n], 0, 0, 0);
    __syncthreads();
  }

  const int col0 = bn * 128 + wn * 64;
  const int row0 = bm * 128 + wm * 64;
  float bl[4];
#pragma unroll
  for (int n = 0; n < 4; ++n) bl[n] = bias[col0 + n * 16 + lr];
#pragma unroll
  for (int m = 0; m < 4; ++m)
#pragma unroll
    for (int i = 0; i < 4; ++i) {
      int row = row0 + m * 16 + lh * 4 + i;
#pragma unroll
      for (int n = 0; n < 4; ++n)
        out[(size_t)row * 1024 + col0 + n * 16 + lr] = acc[m][n][i] + bl[n];
    }
}

extern "C" void kernel_launch(void* const* d_in, const int* in_sizes, int n_in,
                              void* d_out, int out_size, void* d_ws, size_t ws_size,
                              hipStream_t stream) {
  const float* x     = (const float*)d_in[0];
  const float* Wattn = (const float*)d_in[1];
  const float* battn = (const float*)d_in[2];
  const float* Wproj = (const float*)d_in[3];
  const float* bproj = (const float*)d_in[4];
  float* out = (float*)d_out;

  char* ws = (char*)d_ws;
  unsigned short* xb  = (unsigned short*)(ws);                  // 8 MB  x bf16
  unsigned short* wat = (unsigned short*)(ws + (8ull  << 20));  // 6 MB
  unsigned short* wpt = (unsigned short*)(ws + (14ull << 20));  // 2 MB
  unsigned short* qa  = (unsigned short*)(ws + (16ull << 20));  // 8 MB
  unsigned short* ka  = (unsigned short*)(ws + (24ull << 20));  // 8 MB
  unsigned short* va  = (unsigned short*)(ws + (32ull << 20));  // 8 MB  V^T [BH][D][T]
  unsigned short* ob  = (unsigned short*)(ws + (40ull << 20));  // 8 MB  attn out [B,T,C]
  float2* cs          = (float2*)(ws + (48ull << 20));          // 512 KB

  k_cvt<<<(4096 * 1024 / 4) / 256, 256, 0, stream>>>(x, xb, 4096 * 1024 / 4);
  k_tr<<<(3072 * 1024 / 8) / 256, 256, 0, stream>>>(Wattn, wat, 1024, 3072);
  k_tr<<<(1024 * 1024 / 8) / 256, 256, 0, stream>>>(Wproj, wpt, 1024, 1024);
  k_tab<<<(2048 * 32) / 256, 256, 0, stream>>>(cs);
  k_gemm_qkv<<<dim3(24, 32), 256, 0, stream>>>(xb, wat, battn, cs, qa, ka, va);
  k_attn<<<512, 256, 0, stream>>>(qa, ka, va, ob);
  k_gemm_proj<<<dim3(8, 32), 256, 0, stream>>>(ob, wpt, bproj, out);
}

// Round 7
// 138.764 us; speedup vs baseline: 1.0446x; 1.0446x over previous
//
#include <hip/hip_runtime.h>
#include <cstdint>
#include <cstddef>

// Problem constants: B=2, T=2048, C=1024, H=16, D=64
#define SEQ_T 2048
#define NHEAD 16

typedef __attribute__((ext_vector_type(8))) short short8;
typedef __attribute__((ext_vector_type(4))) float f32x4;
typedef __attribute__((ext_vector_type(16))) float f32x16;

__device__ __forceinline__ unsigned short f2bf(float f) {
  union { float f; unsigned int u; } v; v.f = f;
  return (unsigned short)((v.u + 0x7FFFu + ((v.u >> 16) & 1u)) >> 16);
}

__device__ __forceinline__ unsigned cvtpk(float lo, float hi) {
  unsigned r;
  asm("v_cvt_pk_bf16_f32 %0, %1, %2" : "=v"(r) : "v"(lo), "v"(hi));
  return r;
}

// permlane32_swap via builtin (compiler inserts the required hazard waits)
#if __has_builtin(__builtin_amdgcn_permlane32_swap)
__device__ __forceinline__ void plswap(unsigned& a, unsigned& b) {
  auto r = __builtin_amdgcn_permlane32_swap(a, b, false, false);
  a = r[0];
  b = r[1];
}
#else
__device__ __forceinline__ void plswap(unsigned& a, unsigned& b) {
  asm volatile("s_nop 1\n\tv_permlane32_swap_b32 %0, %1\n\ts_nop 1"
               : "+v"(a), "+v"(b));
}
#endif

__device__ __forceinline__ float xhalf_max(float x) {
  unsigned a = __builtin_bit_cast(unsigned, x), b = a;
  plswap(a, b);
  return fmaxf(__builtin_bit_cast(float, a), __builtin_bit_cast(float, b));
}
__device__ __forceinline__ float xhalf_add(float x) {
  unsigned a = __builtin_bit_cast(unsigned, x), b = a;
  plswap(a, b);
  return __builtin_bit_cast(float, a) + __builtin_bit_cast(float, b);
}

__device__ __forceinline__ float vmax16(const f32x16 v) {
  float a0 = fmaxf(v[0], v[8]),  a1 = fmaxf(v[1], v[9]);
  float a2 = fmaxf(v[2], v[10]), a3 = fmaxf(v[3], v[11]);
  float a4 = fmaxf(v[4], v[12]), a5 = fmaxf(v[5], v[13]);
  float a6 = fmaxf(v[6], v[14]), a7 = fmaxf(v[7], v[15]);
  float b0 = fmaxf(a0, a4), b1 = fmaxf(a1, a5);
  float b2 = fmaxf(a2, a6), b3 = fmaxf(a3, a7);
  return fmaxf(fmaxf(b0, b1), fmaxf(b2, b3));
}

__device__ __forceinline__ void gl_lds16(const void* g, void* l) {
  __builtin_amdgcn_global_load_lds(
      (__attribute__((address_space(1))) void*)(void*)g,
      (__attribute__((address_space(3))) void*)l, 16, 0, 0);
}

// ---------- fp32 -> bf16 convert (vectorized) ----------
__global__ void k_cvt(const float* __restrict__ in, unsigned short* __restrict__ out, int n4) {
  int i = blockIdx.x * 256 + threadIdx.x;
  if (i >= n4) return;
  float4 v = ((const float4*)in)[i];
  unsigned long long pk = (unsigned long long)f2bf(v.x)
                        | ((unsigned long long)f2bf(v.y) << 16)
                        | ((unsigned long long)f2bf(v.z) << 32)
                        | ((unsigned long long)f2bf(v.w) << 48);
  ((unsigned long long*)out)[i] = pk;
}

// ---------- [K,N] fp32 -> [N,K] bf16 transpose-convert ----------
__global__ void k_tr(const float* __restrict__ in, unsigned short* __restrict__ out, int K, int N) {
  int idx = blockIdx.x * 256 + threadIdx.x;
  int n = idx % N;
  int k0 = (idx / N) * 8;
  short8 v;
#pragma unroll
  for (int j = 0; j < 8; ++j)
    v[j] = (short)f2bf(in[(size_t)(k0 + j) * N + n]);
  *(short8*)&out[(size_t)n * K + k0] = v;
}

// ---------- RoPE cos/sin table [T][32] ----------
__global__ void k_tab(float2* __restrict__ tab) {
  int idx = blockIdx.x * 256 + threadIdx.x;
  int t = idx >> 5, i = idx & 31;
  float inv = powf(10000.0f, -(float)(2 * i) / 64.0f);
  float f = (float)t * inv;
  tab[idx] = make_float2(cosf(f), sinf(f));
}

// ---------- GEMM1: qkv = x @ W_attn^T(+b), fused RoPE; q/k -> [B,H,T,D], v -> V^T [B,H,D,T] ----------
__global__ void k_gemm_qkv(const unsigned short* __restrict__ A,
                           const unsigned short* __restrict__ Bt,
                           const float* __restrict__ bias,
                           const float2* __restrict__ cs,
                           unsigned short* __restrict__ qo,
                           unsigned short* __restrict__ ko,
                           unsigned short* __restrict__ vo) {
  __shared__ unsigned short lA[128 * 32];
  __shared__ unsigned short lB[128 * 32];
  const int K = 1024;
  const int bn = blockIdx.x, bm = blockIdx.y;
  const int tid = threadIdx.x, w = tid >> 6, l = tid & 63;
  const int lr = l & 15, lh = l >> 4;
  const int wm = w >> 1, wn = w & 1;

  f32x4 acc[4][4];
#pragma unroll
  for (int m = 0; m < 4; ++m)
#pragma unroll
    for (int n = 0; n < 4; ++n)
#pragma unroll
      for (int i = 0; i < 4; ++i) acc[m][n][i] = 0.f;

  const unsigned short* ga0 = A + (size_t)(bm * 128 + w * 16 + (l >> 2)) * K + (l & 3) * 8;
  const unsigned short* gb0 = Bt + (size_t)(bn * 128 + w * 16 + (l >> 2)) * K + (l & 3) * 8;
  unsigned short* la0 = &lA[w * 512];
  unsigned short* la1 = &lA[(w + 4) * 512];
  unsigned short* lb0 = &lB[w * 512];
  unsigned short* lb1 = &lB[(w + 4) * 512];

  for (int kt = 0; kt < K; kt += 32) {
    gl_lds16(ga0 + kt, la0);
    gl_lds16(ga0 + (size_t)64 * K + kt, la1);
    gl_lds16(gb0 + kt, lb0);
    gl_lds16(gb0 + (size_t)64 * K + kt, lb1);
    __syncthreads();
    short8 af[4], bf[4];
#pragma unroll
    for (int m = 0; m < 4; ++m) af[m] = *(const short8*)&lA[(wm * 64 + m * 16 + lr) * 32 + lh * 8];
#pragma unroll
    for (int n = 0; n < 4; ++n) bf[n] = *(const short8*)&lB[(wn * 64 + n * 16 + lr) * 32 + lh * 8];
#pragma unroll
    for (int m = 0; m < 4; ++m)
#pragma unroll
      for (int n = 0; n < 4; ++n)
        acc[m][n] = __builtin_amdgcn_mfma_f32_16x16x32_bf16(af[m], bf[n], acc[m][n], 0, 0, 0);
    __syncthreads();
  }

  const int col0 = bn * 128 + wn * 64;
  const int row0 = bm * 128 + wm * 64;
  const int sec = col0 >> 10;
  const int hh = (col0 >> 6) & 15;
  float bl[4];
#pragma unroll
  for (int n = 0; n < 4; ++n) bl[n] = bias[col0 + n * 16 + lr];

  if (sec == 2) {
    // V^T epilogue: vo is [B*H][D=64][T=2048]
    const int b = row0 >> 11;
    unsigned short* vtp = vo + (size_t)(b * 16 + hh) * 64 * 2048;
#pragma unroll
    for (int n = 0; n < 4; ++n) {
      int d = n * 16 + lr;
#pragma unroll
      for (int m = 0; m < 4; ++m) {
        int t = (row0 + m * 16 + lh * 4) & 2047;
        unsigned long long pk = (unsigned long long)f2bf(acc[m][n][0] + bl[n])
                              | ((unsigned long long)f2bf(acc[m][n][1] + bl[n]) << 16)
                              | ((unsigned long long)f2bf(acc[m][n][2] + bl[n]) << 32)
                              | ((unsigned long long)f2bf(acc[m][n][3] + bl[n]) << 48);
        *(unsigned long long*)&vtp[(size_t)d * 2048 + t] = pk;
      }
    }
  } else {
    unsigned short* dst = (sec == 0) ? qo : ko;
#pragma unroll
    for (int m = 0; m < 4; ++m)
#pragma unroll
      for (int i = 0; i < 4; ++i) {
        int row = row0 + m * 16 + lh * 4 + i;
        int t = row & 2047, b = row >> 11;
        size_t ob = ((size_t)(b * 16 + hh) * 2048 + t) * 64;
#pragma unroll
        for (int n = 0; n < 4; ++n) {
          float v = acc[m][n][i] + bl[n];
          float pv = acc[m][n ^ 2][i] + bl[n ^ 2];
          int d = n * 16 + lr;
          float2 c = cs[t * 32 + (d & 31)];
          float rot = (d < 32) ? -pv : pv;
          dst[ob + d] = f2bf(v * c.x + rot * c.y);
        }
      }
  }
}

// ---------- flash attention, 32x32 MFMA, kv-split 8-wave blocks ----------
// grid 512 (XCD-chunked), 512 thr = 8 waves: wq=w&3 (32-q subtile), wk=w>>2 (64-kv half).
// Each wave keeps an independent (m,l,O) stream over its kv-half of every 128-kv tile;
// one flash-combine merge via LDS at the epilogue. 2 blocks/CU x 8 waves = 16 waves/CU.
__global__ __launch_bounds__(512, 4) void k_attn(const unsigned short* __restrict__ Q,
                       const unsigned short* __restrict__ Kg,
                       const unsigned short* __restrict__ VT,
                       unsigned short* __restrict__ O) {
  __shared__ unsigned short kl[2][128 * 64];   // [kv][d], chunk-swizzled ^(kv&7)
  __shared__ unsigned short vl[2][64 * 128];   // [d][kv], chunk-swizzled ^(d&15)
  const int id = blockIdx.x;
  const int xcd = id & 7, u = id >> 3;
  const int g = u >> 4;
  const int bh = xcd * 4 + g;
  const int s = (u + g * 4) & 15;              // per-head slot shift (balance)
  const int qt = (s & 1) ? 15 - (s >> 1) : (s >> 1);
  const int tid = threadIdx.x, w = tid >> 6, l = tid & 63;
  const int wq = w & 3, wk = w >> 2;
  const int lq = l & 31, hi = l >> 5;
  const size_t base = (size_t)bh * SEQ_T * 64;
  const float CE = 0.18033688f;   // 0.125 * log2(e)
  const float DTHR = 44.3614f;    // 8 / CE

  // Q fragments (B-operand): lane holds Q[qrow][c*16 + hi*8 + j]
  const int qrow = qt * 128 + wq * 32 + lq;
  short8 qf[4];
#pragma unroll
  for (int c = 0; c < 4; ++c)
    qf[c] = *(const short8*)&Q[base + (size_t)qrow * 64 + c * 16 + hi * 8];

  // staging source bases (pre-swizzled global source, linear LDS dest)
  const int kv0 = tid >> 3;                    // 0..63
  const unsigned short* ks0 = Kg + base + (size_t)kv0 * 64 + (((tid & 7) ^ (kv0 & 7)) * 8);
  const int dv0 = tid >> 4;                    // 0..31
  const unsigned short* vs0 = VT + base + (size_t)dv0 * 2048 + (((tid & 15) ^ (dv0 & 15)) * 8);

#define STAGE(KT, BSEL) do { \
    const unsigned short* kp_ = ks0 + (size_t)(KT) * 8192; \
    const unsigned short* vp_ = vs0 + (size_t)(KT) * 128;  \
    unsigned short* kd_ = &kl[BSEL][w * 512]; \
    unsigned short* vd_ = &vl[BSEL][w * 512]; \
    gl_lds16(kp_,         kd_);        gl_lds16(kp_ + 4096,  kd_ + 4096); \
    gl_lds16(vp_,         vd_);        gl_lds16(vp_ + 65536, vd_ + 4096); \
  } while (0)

  float mi = -1.0e30f, li = 0.f;               // init > mask value (kv-split safety)
  f32x16 oc0, oc1;
#pragma unroll
  for (int r = 0; r < 16; ++r) { oc0[r] = 0.f; oc1[r] = 0.f; }

  const int nkt = qt + 1;
  STAGE(0, 0);
  __syncthreads();

  for (int kt = 0; kt < nkt; ++kt) {
    const int cur = kt & 1;
    if (kt + 1 < nkt) STAGE(kt + 1, cur ^ 1);
    const unsigned short* kb = &kl[cur][0];
    const unsigned short* vb = &vl[cur][0];

    // S^T = K Q^T over this wave's 64-kv half: 2 kv-tiles of 32
    f32x16 st[2];
#pragma unroll
    for (int tt = 0; tt < 2; ++tt)
#pragma unroll
      for (int r = 0; r < 16; ++r) st[tt][r] = 0.f;

    __builtin_amdgcn_s_setprio(1);
#pragma unroll
    for (int tt = 0; tt < 2; ++tt) {
      const int rowb = (wk * 64 + tt * 32 + lq) * 64;
#pragma unroll
      for (int c = 0; c < 4; ++c) {
        const short8 kf = *(const short8*)&kb[rowb + (((c * 2 + hi) ^ (lq & 7)) * 8)];
        st[tt] = __builtin_amdgcn_mfma_f32_32x32x16_bf16(kf, qf[c], st[tt], 0, 0, 0);
      }
    }
    __builtin_amdgcn_s_setprio(0);

    if (kt == nkt - 1) {   // diagonal: causal mask (unscaled scores)
#pragma unroll
      for (int tt = 0; tt < 2; ++tt)
#pragma unroll
        for (int r = 0; r < 16; ++r) {
          int kvg = kt * 128 + wk * 64 + tt * 32 + (r & 3) + 8 * (r >> 2) + 4 * hi;
          if (kvg > qrow) st[tt][r] = -3.0e38f;
        }
    }

    // tile max (own 32 + partner half)
    float tm = xhalf_max(fmaxf(vmax16(st[0]), vmax16(st[1])));

    // T13 defer-rescale
    if (!__all(tm <= mi + DTHR)) {
      float mn = fmaxf(mi, tm);
      float scq = exp2f((mi - mn) * CE);
      mi = mn;
      li *= scq;
#pragma unroll
      for (int r = 0; r < 16; ++r) {
        float sc_r = __shfl(scq, (r & 3) + 8 * (r >> 2) + 4 * hi, 64);
        oc0[r] *= sc_r;
        oc1[r] *= sc_r;
      }
    }

    // exp pass (in place) + row sum
    const float nb = mi * CE;
    float rs = 0.f;
#pragma unroll
    for (int tt = 0; tt < 2; ++tt)
#pragma unroll
      for (int r = 0; r < 16; ++r) {
        float p = exp2f(fmaf(st[tt][r], CE, -nb));
        st[tt][r] = p;
        rs += p;
      }
    li += xhalf_add(rs);

    // pack P into PV A-fragments: per 16-kv block, 4 cvt_pk + 2 permlane32_swap
    short8 pa[4];
#pragma unroll
    for (int kc = 0; kc < 4; ++kc) {
      const int tt = kc >> 1, o = (kc & 1) * 8;
      unsigned w0 = cvtpk(st[tt][o + 0], st[tt][o + 1]);
      unsigned w1 = cvtpk(st[tt][o + 2], st[tt][o + 3]);
      unsigned w2 = cvtpk(st[tt][o + 4], st[tt][o + 5]);
      unsigned w3 = cvtpk(st[tt][o + 6], st[tt][o + 7]);
      plswap(w0, w2);
      plswap(w1, w3);
      uint4 F;
      F.x = w0; F.y = w1; F.z = w2; F.w = w3;
      pa[kc] = __builtin_bit_cast(short8, F);
    }

    // O += P V over this wave's kv-half : 4 k-chunks x 2 d-tiles
    __builtin_amdgcn_s_setprio(1);
#pragma unroll
    for (int kc = 0; kc < 4; ++kc) {
      const int chs = ((wk * 8 + kc * 2 + hi) ^ (lq & 15)) * 8;
      const short8 vb0 = *(const short8*)&vb[lq * 128 + chs];
      oc0 = __builtin_amdgcn_mfma_f32_32x32x16_bf16(pa[kc], vb0, oc0, 0, 0, 0);
      const short8 vb1 = *(const short8*)&vb[(32 + lq) * 128 + chs];
      oc1 = __builtin_amdgcn_mfma_f32_32x32x16_bf16(pa[kc], vb1, oc1, 0, 0, 0);
    }
    __builtin_amdgcn_s_setprio(0);

    if (kt + 1 < nkt) __syncthreads();
  }

  // ---- epilogue: flash-combine the two kv-half streams, write O [B,T,C] bf16 ----
  __syncthreads();                       // staging/compute done; reuse kl/vl as merge scratch
  float* obuf = (float*)&kl[0][0];       // [wq][32 q][64 d] fp32 = 32 KB
  float* mlb  = (float*)&vl[0][0];       // [wq][32 q][2] (m, l)
  if (wk == 1) {
#pragma unroll
    for (int r = 0; r < 16; ++r) {
      const int q = (r & 3) + 8 * (r >> 2) + 4 * hi;
      obuf[wq * 2048 + q * 64 + lq]      = oc0[r];
      obuf[wq * 2048 + q * 64 + 32 + lq] = oc1[r];
    }
    if (hi == 0) {
      mlb[wq * 64 + lq * 2 + 0] = mi;
      mlb[wq * 64 + lq * 2 + 1] = li;
    }
  }
  __syncthreads();
  if (wk == 0) {
    const int hh = bh & 15, bb = bh >> 4;
#pragma unroll
    for (int r = 0; r < 16; ++r) {
      const int q = (r & 3) + 8 * (r >> 2) + 4 * hi;
      float m0 = __shfl(mi, q, 64), l0 = __shfl(li, q, 64);
      float m1 = mlb[wq * 64 + q * 2 + 0], l1 = mlb[wq * 64 + q * 2 + 1];
      float mm = fmaxf(m0, m1);
      float f0 = exp2f((m0 - mm) * CE), f1 = exp2f((m1 - mm) * CE);
      float inv = 1.0f / (f0 * l0 + f1 * l1);
      float o0 = (f0 * oc0[r] + f1 * obuf[wq * 2048 + q * 64 + lq]) * inv;
      float o1 = (f0 * oc1[r] + f1 * obuf[wq * 2048 + q * 64 + 32 + lq]) * inv;
      int qg = qt * 128 + wq * 32 + q;
      size_t ob = (size_t)(bb * 2048 + qg) * 1024 + hh * 64;
      O[ob + lq]      = f2bf(o0);
      O[ob + 32 + lq] = f2bf(o1);
    }
  }
#undef STAGE
}

// ---------- GEMM2: out = attn_out @ W_proj^T + b (fp32 out) ----------
__global__ void k_gemm_proj(const unsigned short* __restrict__ A,
                            const unsigned short* __restrict__ Bt,
                            const float* __restrict__ bias,
                            float* __restrict__ out) {
  __shared__ unsigned short lA[128 * 32];
  __shared__ unsigned short lB[128 * 32];
  const int K = 1024;
  const int bn = blockIdx.x, bm = blockIdx.y;
  const int tid = threadIdx.x, w = tid >> 6, l = tid & 63;
  const int lr = l & 15, lh = l >> 4;
  const int wm = w >> 1, wn = w & 1;

  f32x4 acc[4][4];
#pragma unroll
  for (int m = 0; m < 4; ++m)
#pragma unroll
    for (int n = 0; n < 4; ++n)
#pragma unroll
      for (int i = 0; i < 4; ++i) acc[m][n][i] = 0.f;

  const unsigned short* ga0 = A + (size_t)(bm * 128 + w * 16 + (l >> 2)) * K + (l & 3) * 8;
  const unsigned short* gb0 = Bt + (size_t)(bn * 128 + w * 16 + (l >> 2)) * K + (l & 3) * 8;
  unsigned short* la0 = &lA[w * 512];
  unsigned short* la1 = &lA[(w + 4) * 512];
  unsigned short* lb0 = &lB[w * 512];
  unsigned short* lb1 = &lB[(w + 4) * 512];

  for (int kt = 0; kt < K; kt += 32) {
    gl_lds16(ga0 + kt, la0);
    gl_lds16(ga0 + (size_t)64 * K + kt, la1);
    gl_lds16(gb0 + kt, lb0);
    gl_lds16(gb0 + (size_t)64 * K + kt, lb1);
    __syncthreads();
    short8 af[4], bf[4];
#pragma unroll
    for (int m = 0; m < 4; ++m) af[m] = *(const short8*)&lA[(wm * 64 + m * 16 + lr) * 32 + lh * 8];
#pragma unroll
    for (int n = 0; n < 4; ++n) bf[n] = *(const short8*)&lB[(wn * 64 + n * 16 + lr) * 32 + lh * 8];
#pragma unroll
    for (int m = 0; m < 4; ++m)
#pragma unroll
      for (int n = 0; n < 4; ++n)
        acc[m][n] = __builtin_amdgcn_mfma_f32_16x16x32_bf16(af[m], bf[n], acc[m][n], 0, 0, 0);
    __syncthreads();
  }

  const int col0 = bn * 128 + wn * 64;
  const int row0 = bm * 128 + wm * 64;
  float bl[4];
#pragma unroll
  for (int n = 0; n < 4; ++n) bl[n] = bias[col0 + n * 16 + lr];
#pragma unroll
  for (int m = 0; m < 4; ++m)
#pragma unroll
    for (int i = 0; i < 4; ++i) {
      int row = row0 + m * 16 + lh * 4 + i;
#pragma unroll
      for (int n = 0; n < 4; ++n)
        out[(size_t)row * 1024 + col0 + n * 16 + lr] = acc[m][n][i] + bl[n];
    }
}

extern "C" void kernel_launch(void* const* d_in, const int* in_sizes, int n_in,
                              void* d_out, int out_size, void* d_ws, size_t ws_size,
                              hipStream_t stream) {
  const float* x     = (const float*)d_in[0];
  const float* Wattn = (const float*)d_in[1];
  const float* battn = (const float*)d_in[2];
  const float* Wproj = (const float*)d_in[3];
  const float* bproj = (const float*)d_in[4];
  float* out = (float*)d_out;

  char* ws = (char*)d_ws;
  unsigned short* xb  = (unsigned short*)(ws);                  // 8 MB  x bf16
  unsigned short* wat = (unsigned short*)(ws + (8ull  << 20));  // 6 MB
  unsigned short* wpt = (unsigned short*)(ws + (14ull << 20));  // 2 MB
  unsigned short* qa  = (unsigned short*)(ws + (16ull << 20));  // 8 MB
  unsigned short* ka  = (unsigned short*)(ws + (24ull << 20));  // 8 MB
  unsigned short* va  = (unsigned short*)(ws + (32ull << 20));  // 8 MB  V^T [BH][D][T]
  unsigned short* ob  = (unsigned short*)(ws + (40ull << 20));  // 8 MB  attn out [B,T,C]
  float2* cs          = (float2*)(ws + (48ull << 20));          // 512 KB

  k_cvt<<<(4096 * 1024 / 4) / 256, 256, 0, stream>>>(x, xb, 4096 * 1024 / 4);
  k_tr<<<(3072 * 1024 / 8) / 256, 256, 0, stream>>>(Wattn, wat, 1024, 3072);
  k_tr<<<(1024 * 1024 / 8) / 256, 256, 0, stream>>>(Wproj, wpt, 1024, 1024);
  k_tab<<<(2048 * 32) / 256, 256, 0, stream>>>(cs);
  k_gemm_qkv<<<dim3(24, 32), 256, 0, stream>>>(xb, wat, battn, cs, qa, ka, va);
  k_attn<<<512, 512, 0, stream>>>(qa, ka, va, ob);
  k_gemm_proj<<<dim3(8, 32), 256, 0, stream>>>(ob, wpt, bproj, out);
}